// Round 10
// baseline (6073.606 us; speedup 1.0000x reference)
//
#include <hip/hip_runtime.h>
#include <hip/hip_fp16.h>

#define LOG2E 1.44269504088896340736f
#define BB 256
#define TT 128
#define SS 128
#define UU 256
// |dv| threshold for "unfold was identity" (see R1/R2/R7 notes): must sit above 1 f16
// ulp of v (4.88e-4 dither); post-freeze drift <= eps*c/(1-c), c ~ 0.03-0.07 -> ~9e-5.
#define CONV_EPS 1.2e-3f

typedef unsigned int u32;

__device__ __forceinline__ __half2 uh(u32 x) { union { u32 u; __half2 h; } c; c.u = x; return c.h; }
__device__ __forceinline__ u32 hu(__half2 h) { union { u32 u; __half2 h2; } c; c.h2 = h; return c.u; }

// ---------------- parameter precompute (pair-packed) ----------------
// sigmoid(sigma*(v-mu)) = 1/(1+2^(a*v+b)), a=-sigma*log2e, b=sigma*mu*log2e
// Two consecutive pre-rows (2*i2, 2*i2+1) packed per entry:
//   uint4{ half2(a0,a1), half2(b0,b1), half2(wP0,wP1), half2(wN0,wN1) }  (16 B)
__global__ __launch_bounds__(256) void prep_kernel(
    const float* __restrict__ sensory_w, const float* __restrict__ sensory_mu,
    const float* __restrict__ sensory_sigma, const float* __restrict__ sensory_erev,
    const float* __restrict__ w, const float* __restrict__ mu,
    const float* __restrict__ sigma, const float* __restrict__ erev,
    const float* __restrict__ gleak, const float* __restrict__ vleak,
    const float* __restrict__ cm,
    uint4* __restrict__ rabw4, uint4* __restrict__ sabw4,
    float* __restrict__ cmt, float* __restrict__ gnum, float* __restrict__ cden)
{
    int e = blockIdx.x * 256 + threadIdx.x;   // e = i2*256 + j
    if (e < (UU / 2) * UU) {
        int i2 = e >> 8, j = e & 255;
        int r0 = (2 * i2) * UU + j, r1 = r0 + UU;
        float sg0 = sigma[r0], sg1 = sigma[r1];
        float m0 = mu[r0], m1 = mu[r1];
        float wq0 = log1pf(expf(w[r0])), wq1 = log1pf(expf(w[r1]));
        bool p0 = erev[r0] > 0.0f, p1 = erev[r1] > 0.0f;
        uint4 o;
        o.x = hu(__floats2half2_rn(-sg0 * LOG2E, -sg1 * LOG2E));
        o.y = hu(__floats2half2_rn(sg0 * m0 * LOG2E, sg1 * m1 * LOG2E));
        o.z = hu(__floats2half2_rn(p0 ? wq0 : 0.0f, p1 ? wq1 : 0.0f));
        o.w = hu(__floats2half2_rn(p0 ? 0.0f : wq0, p1 ? 0.0f : wq1));
        rabw4[e] = o;
    }
    if (e < (SS / 2) * UU) {
        int i2 = e >> 8, j = e & 255;
        int r0 = (2 * i2) * UU + j, r1 = r0 + UU;
        float sg0 = sensory_sigma[r0], sg1 = sensory_sigma[r1];
        float m0 = sensory_mu[r0], m1 = sensory_mu[r1];
        float wq0 = log1pf(expf(sensory_w[r0])), wq1 = log1pf(expf(sensory_w[r1]));
        bool p0 = sensory_erev[r0] > 0.0f, p1 = sensory_erev[r1] > 0.0f;
        uint4 o;
        o.x = hu(__floats2half2_rn(-sg0 * LOG2E, -sg1 * LOG2E));
        o.y = hu(__floats2half2_rn(sg0 * m0 * LOG2E, sg1 * m1 * LOG2E));
        o.z = hu(__floats2half2_rn(p0 ? wq0 : 0.0f, p1 ? wq1 : 0.0f));
        o.w = hu(__floats2half2_rn(p0 ? 0.0f : wq0, p1 ? 0.0f : wq1));
        sabw4[e] = o;
    }
    if (e < UU) {
        float gl = log1pf(expf(gleak[e]));
        float c = log1pf(expf(cm[e])) * 6.0f;   // ODE_UNFOLDS=6, ts=1
        cmt[e] = c;
        gnum[e] = gl * vleak[e];
        cden[e] = c + gl + 1e-8f;
    }
}

// R7 STEP2 (best measured): scalar hexp2/hrcp (quarter-rate, proven by R9 that
// replacing them with full-rate glue is a wash) + packed z / packed accumulate.
// hrcp(inf)=0 saturates safely -> no clamp needed.
#define STEP2(A2U, B2U, WP2U, WN2U, V2U) do {                                \
    u32 z_ = hu(__hfma2(uh(A2U), uh(V2U), uh(B2U)));                         \
    __half el_ = hexp2(__ushort_as_half((unsigned short)(z_ & 0xffffu)));    \
    __half eh_ = hexp2(__ushort_as_half((unsigned short)(z_ >> 16)));        \
    __half dl_ = __hadd(el_, __float2half(1.0f));                            \
    __half dh_ = __hadd(eh_, __float2half(1.0f));                            \
    __half2 s2_ = __halves2half2(hrcp(dl_), hrcp(dh_));                      \
    accP2 = __hfma2(uh(WP2U), s2_, accP2);                                   \
    accN2 = __hfma2(uh(WN2U), s2_, accN2);                                   \
} while (0)

#define FLUSH2() do {                                                        \
    float2 fp_ = __half22float2(accP2);                                      \
    float2 fn_ = __half22float2(accN2);                                      \
    P += fp_.x + fp_.y; N += fn_.x + fn_.y;                                  \
    accP2 = uh(0u); accN2 = uh(0u);                                          \
} while (0)

// ---------------- main kernel: 1 block = 1 batch element, 16 waves ----------------
// wave (qi=wv&3, qj=wv>>2): column j = 64*qj + l.
// Recurrent row-pairs per wave: 24 in registers (pairs 24qi..+23, 96 VGPRs) + 8 from
// LDS (pairs 96+8qi..+7). v lane-distributed: lane l holds v[u(l)]; pair-packed v
// broadcast built once per forward pass with one shfl_xor; one readlane per STEP2.
//
// R10 ROTATED unfold loop: {v-update -> conv-check -> STEP2s -> barrier} instead of
// {STEP2s -> barrier -> v-update -> conv-check}. The old order always executed one
// provably-identity STEP2 block after convergence (detection lag); rotation moves the
// exit BEFORE the expensive block: forward passes per timestep drop from k+2 to k+1
// (k = first unfold with block-wide dv<=eps). Same dv criterion, same triple-buffered
// flag discipline (slot write/read/reset pairs all barrier-separated; all breaks are
// block-uniform so no barrier divergence).
__global__ __launch_bounds__(1024, 4) void ltc_kernel(
    const float* __restrict__ x,
    const float* __restrict__ input_w, const float* __restrict__ input_b,
    const float* __restrict__ halt_w, const float* __restrict__ halt_b,
    const float* __restrict__ out_w, const float* __restrict__ out_b,
    const uint4* __restrict__ rabw4, const uint4* __restrict__ sabw4,
    const float* __restrict__ cmt_g, const float* __restrict__ gnum_g,
    const float* __restrict__ cden_g,
    float* __restrict__ readout, float* __restrict__ h_state, float* __restrict__ ponder_out)
{
    const int b = blockIdx.x, tid = threadIdx.x;
    const int wv = tid >> 6, l = tid & 63;
    const int qi = wv & 3, qj = wv >> 2;
    const int j = (qj << 6) + l;
    const int u = (l < 48) ? (48 * qi + l) : (192 + 16 * qi + (l - 48));

    __shared__ uint4 rlds4[32 * UU];         // 128 KB: row-pairs 96..127 (rows 192..255)
    __shared__ float2 part[2][4][UU];        // 16 KB: (P,N) partials, double-buffered
    __shared__ __half2 xinh2[SS / 2];
    __shared__ float red[4];
    __shared__ int viol[3];                  // triple-buffered "dv_s violated eps" flag

    // stage LDS-resident row-pairs (once): 32*256 uint4
    for (int m = 0; m < 8; ++m) {
        int f = m * 1024 + tid;
        rlds4[f] = rabw4[96 * 256 + f];
    }

    // register-resident row-pairs (once): 96 VGPRs (pairs 24qi..24qi+23)
    u32 rp_a2[24], rp_b2[24], rp_wp2[24], rp_wn2[24];
#pragma unroll
    for (int kk = 0; kk < 24; ++kk) {
        uint4 tp = rabw4[((24 * qi + kk) << 8) + j];
        rp_a2[kk] = tp.x; rp_b2[kk] = tp.y; rp_wp2[kk] = tp.z; rp_wn2[kk] = tp.w;
    }

    const float cmtu = cmt_g[u], gnu = gnum_g[u], cdu = cden_g[u];
    const float hwu = halt_w[u], owu = out_w[u], obu = out_b[u];
    const float hb = halt_b[0];
    float iw = 0.f, ibv = 0.f;
    if (tid < SS) { iw = input_w[tid]; ibv = input_b[tid]; }

    float v = 0.0f;
    int vhb = 0;                  // f16 bits of v (for readlane broadcast)
    float pond = 0.0f;
    __syncthreads();

    for (int t = 0; t < TT; ++t) {
        // ---- input mapping (f16 for broadcast use) ----
        if (tid < SS)
            ((__half*)xinh2)[tid] =
                __float2half(fmaf(x[((size_t)b * TT + t) * SS + tid], iw, ibv));
        __syncthreads();
        if (tid == 0) viol[0] = 0;   // slot for dv_0; slots 1,2 reset by dv_0/dv_1 iters

        // forward pass: STEP2s with current v -> part[pw_]
        auto forward = [&](int pw_) {
            int nbv = __shfl_xor(vhb, 1, 64);
            int vpk = (vhb & 0xffff) | (nbv << 16);
            float P = 0.f, N = 0.f;
            __half2 accP2 = uh(0u), accN2 = uh(0u);
#pragma unroll
            for (int kk = 0; kk < 24; ++kk) {
                u32 v2 = (u32)__builtin_amdgcn_readlane(vpk, 2 * kk);
                STEP2(rp_a2[kk], rp_b2[kk], rp_wp2[kk], rp_wn2[kk], v2);
                if ((kk & 7) == 7) FLUSH2();
            }
#pragma unroll
            for (int m = 0; m < 8; ++m) {
                uint4 prr = rlds4[((8 * qi + m) << 8) + j];
                u32 v2 = (u32)__builtin_amdgcn_readlane(vpk, 48 + 2 * m);
                STEP2(prr.x, prr.y, prr.z, prr.w, v2);
            }
            FLUSH2();
            part[pw_][qi][j] = make_float2(P, N);
        };

        // ---- sensory partials: row-pairs [16qi, 16qi+16), streamed from L2 ----
        {
            float P = 0.f, N = 0.f;
            __half2 accP2 = uh(0u), accN2 = uh(0u);
#pragma unroll 1
            for (int c = 0; c < 8; ++c) {
                int p0 = 16 * qi + 2 * c;
                uint4 q0 = sabw4[(p0 << 8) + j];
                uint4 q1 = sabw4[((p0 + 1) << 8) + j];
                u32 x0 = hu(xinh2[p0]);
                u32 x1 = hu(xinh2[p0 + 1]);
                STEP2(q0.x, q0.y, q0.z, q0.w, x0);
                STEP2(q1.x, q1.y, q1.z, q1.w, x1);
                if ((c & 3) == 3) FLUSH2();
            }
            part[0][qi][j] = make_float2(P, N);
        }
        __syncthreads();
        float basen, based;
        {
            float2 s0 = part[0][0][u], s1 = part[0][1][u];
            float2 s2 = part[0][2][u], s3 = part[0][3][u];
            float Ps = s0.x + s1.x + s2.x + s3.x;
            float Ns = s0.y + s1.y + s2.y + s3.y;
            basen = (Ps - Ns) + gnu;
            based = (Ps + Ns) + cdu;
        }

        int pw = 1;                   // first forward targets slot 1 (slot 0 = sensory,
                                      // its basen reads complete before slot-0 reuse,
                                      // which happens only after the next barrier)
        float accA = 0.0f, halt_sum = 0.0f, rem = 0.0f;
        int nupd = 0;
        int s = 0;                    // dv counter within this timestep
        bool tconv = false;           // fixed point reached -> remaining unfolds identity
        float pr = 0.0f;              // cached halting prob (valid while tconv)

        // ---- ACT loop (uniform early exit) ----
#pragma unroll 1
        for (int n = 0; n < 10; ++n) {
            // step-top check: catches convergence at the final vupdate of the previous
            // step (flag written before the halting-phase barrier -> race-free read).
            if (!tconv && s >= 1 && viol[(s - 1) % 3] == 0) tconv = true;
            if (!tconv) {
                forward(pw); __syncthreads();
#pragma unroll 1
                for (int uu = 1; uu <= 6; ++uu) {
                    // v-update from part[pw] (written by preceding forward; barriered)
                    float2 p0 = part[pw][0][u], p1 = part[pw][1][u];
                    float2 p2 = part[pw][2][u], p3 = part[pw][3][u];
                    float Pt = p0.x + p1.x + p2.x + p3.x;
                    float Nt = p0.y + p1.y + p2.y + p3.y;
                    float num = (Pt - Nt) + basen;
                    float den = (Pt + Nt) + based;
                    float vn = fmaf(cmtu, v, num) * __builtin_amdgcn_rcpf(den);
                    float dv = fabsf(vn - v);
                    v = vn;
                    vhb = (int)__half_as_ushort(__float2half(v));
                    // flag discipline: write dv_s -> slot s%3; reset slot (s+1)%3 for
                    // dv_{s+1}; read dv_{s-1}'s verdict (written last iter, barriered).
                    int aw = __all(dv <= CONV_EPS);
                    if (l == 0 && !aw) viol[s % 3] = 1;
                    if (tid == 0) viol[(s + 1) % 3] = 0;
                    bool fin = (s >= 1) && (viol[(s - 1) % 3] == 0);
                    ++s;
                    if (fin) { tconv = true; break; }   // v already final: skip STEP2s
                    if (uu == 6) break;                  // 6 unfolds complete
                    pw ^= 1;
                    forward(pw); __syncthreads();
                }

                // halting p = sigmoid(v . halt_w + hb); qj==0 waves hold all 256 units
                if (qj == 0) {
                    float hp = v * hwu;
                    hp += __shfl_down(hp, 32, 64);
                    hp += __shfl_down(hp, 16, 64);
                    hp += __shfl_down(hp, 8, 64);
                    hp += __shfl_down(hp, 4, 64);
                    hp += __shfl_down(hp, 2, 64);
                    hp += __shfl_down(hp, 1, 64);
                    if (l == 0) red[qi] = hp;
                }
                __syncthreads();
                float dot = red[0] + red[1] + red[2] + red[3] + hb;
                pr = __builtin_amdgcn_rcpf(1.0f + __builtin_amdgcn_exp2f(-dot * LOG2E));
            }
            // scalar ACT accounting (exact reference semantics)
            float new_sum = halt_sum + pr;
            bool halting = (n == 9) || (new_sum >= 0.99f);
            float r = 1.0f - halt_sum;
            float wgt = halting ? r : pr;
            accA = fmaf(wgt, v, accA);
            if (halting) rem += r;
            halt_sum = new_sum;
            ++nupd;
            if (halting) break;
        }

        // ---- t epilogue: new_state = accA ----
        if (qj == 0)
            readout[((size_t)b * TT + t) * UU + u] = fmaf(accA, owu, obu);
        v = accA;
        vhb = (int)__half_as_ushort(__float2half(v));
        pond += (float)nupd + rem;
    }

    if (qj == 0) h_state[(size_t)b * UU + u] = v;
    if (tid == 0) atomicAdd(ponder_out, pond * (1.0f / BB));
}

// ---------------- launch ----------------
extern "C" void kernel_launch(void* const* d_in, const int* in_sizes, int n_in,
                              void* d_out, int out_size, void* d_ws, size_t ws_size,
                              hipStream_t stream)
{
    const float* x             = (const float*)d_in[0];
    const float* input_w       = (const float*)d_in[1];
    const float* input_b       = (const float*)d_in[2];
    const float* sensory_w     = (const float*)d_in[3];
    const float* sensory_mu    = (const float*)d_in[4];
    const float* sensory_sigma = (const float*)d_in[5];
    const float* sensory_erev  = (const float*)d_in[6];
    const float* w             = (const float*)d_in[7];
    const float* mu            = (const float*)d_in[8];
    const float* sigma         = (const float*)d_in[9];
    const float* erev          = (const float*)d_in[10];
    const float* gleak         = (const float*)d_in[11];
    const float* vleak         = (const float*)d_in[12];
    const float* cm            = (const float*)d_in[13];
    const float* output_w      = (const float*)d_in[14];
    const float* output_b      = (const float*)d_in[15];
    const float* halt_w        = (const float*)d_in[16];
    const float* halt_b        = (const float*)d_in[17];

    float* readout = (float*)d_out;
    float* h_state = readout + (size_t)BB * TT * UU;
    float* ponder  = h_state + (size_t)BB * UU;

    char* wsb = (char*)d_ws;
    uint4* rabw4 = (uint4*)wsb;  wsb += (size_t)(UU / 2) * UU * sizeof(uint4);
    uint4* sabw4 = (uint4*)wsb;  wsb += (size_t)(SS / 2) * UU * sizeof(uint4);
    float* cmt  = (float*)wsb;  wsb += (size_t)UU * 4;
    float* gnum = (float*)wsb;  wsb += (size_t)UU * 4;
    float* cden = (float*)wsb;  wsb += (size_t)UU * 4;

    (void)hipMemsetAsync(ponder, 0, sizeof(float), stream);
    prep_kernel<<<128, 256, 0, stream>>>(
        sensory_w, sensory_mu, sensory_sigma, sensory_erev,
        w, mu, sigma, erev, gleak, vleak, cm,
        rabw4, sabw4, cmt, gnum, cden);
    ltc_kernel<<<BB, 1024, 0, stream>>>(
        x, input_w, input_b, halt_w, halt_b, output_w, output_b,
        rabw4, sabw4, cmt, gnum, cden,
        readout, h_state, ponder);
}

// Round 11
// 3856.857 us; speedup vs baseline: 1.5748x; 1.5748x over previous
//
#include <hip/hip_runtime.h>
#include <hip/hip_fp16.h>

#define LOG2E 1.44269504088896340736f
#define BB 256
#define TT 128
#define SS 128
#define UU 256
// |dv| threshold for "unfold was identity" (see R1/R2/R7 notes): must sit above 1 f16
// ulp of v (4.88e-4 dither); post-freeze drift <= eps*c/(1-c), c ~ 0.03-0.07 -> ~9e-5.
#define CONV_EPS 1.2e-3f

typedef unsigned int u32;

__device__ __forceinline__ __half2 uh(u32 x) { union { u32 u; __half2 h; } c; c.u = x; return c.h; }
__device__ __forceinline__ u32 hu(__half2 h) { union { u32 u; __half2 h2; } c; c.h2 = h; return c.u; }

// ---------------- parameter precompute (pair-packed) ----------------
// sigmoid(sigma*(v-mu)) = 1/(1+2^(a*v+b)), a=-sigma*log2e, b=sigma*mu*log2e
// Two consecutive pre-rows (2*i2, 2*i2+1) packed per entry:
//   uint4{ half2(a0,a1), half2(b0,b1), half2(wP0,wP1), half2(wN0,wN1) }  (16 B)
__global__ __launch_bounds__(256) void prep_kernel(
    const float* __restrict__ sensory_w, const float* __restrict__ sensory_mu,
    const float* __restrict__ sensory_sigma, const float* __restrict__ sensory_erev,
    const float* __restrict__ w, const float* __restrict__ mu,
    const float* __restrict__ sigma, const float* __restrict__ erev,
    const float* __restrict__ gleak, const float* __restrict__ vleak,
    const float* __restrict__ cm,
    uint4* __restrict__ rabw4, uint4* __restrict__ sabw4,
    float* __restrict__ cmt, float* __restrict__ gnum, float* __restrict__ cden)
{
    int e = blockIdx.x * 256 + threadIdx.x;   // e = i2*256 + j
    if (e < (UU / 2) * UU) {
        int i2 = e >> 8, j = e & 255;
        int r0 = (2 * i2) * UU + j, r1 = r0 + UU;
        float sg0 = sigma[r0], sg1 = sigma[r1];
        float m0 = mu[r0], m1 = mu[r1];
        float wq0 = log1pf(expf(w[r0])), wq1 = log1pf(expf(w[r1]));
        bool p0 = erev[r0] > 0.0f, p1 = erev[r1] > 0.0f;
        uint4 o;
        o.x = hu(__floats2half2_rn(-sg0 * LOG2E, -sg1 * LOG2E));
        o.y = hu(__floats2half2_rn(sg0 * m0 * LOG2E, sg1 * m1 * LOG2E));
        o.z = hu(__floats2half2_rn(p0 ? wq0 : 0.0f, p1 ? wq1 : 0.0f));
        o.w = hu(__floats2half2_rn(p0 ? 0.0f : wq0, p1 ? 0.0f : wq1));
        rabw4[e] = o;
    }
    if (e < (SS / 2) * UU) {
        int i2 = e >> 8, j = e & 255;
        int r0 = (2 * i2) * UU + j, r1 = r0 + UU;
        float sg0 = sensory_sigma[r0], sg1 = sensory_sigma[r1];
        float m0 = sensory_mu[r0], m1 = sensory_mu[r1];
        float wq0 = log1pf(expf(sensory_w[r0])), wq1 = log1pf(expf(sensory_w[r1]));
        bool p0 = sensory_erev[r0] > 0.0f, p1 = sensory_erev[r1] > 0.0f;
        uint4 o;
        o.x = hu(__floats2half2_rn(-sg0 * LOG2E, -sg1 * LOG2E));
        o.y = hu(__floats2half2_rn(sg0 * m0 * LOG2E, sg1 * m1 * LOG2E));
        o.z = hu(__floats2half2_rn(p0 ? wq0 : 0.0f, p1 ? wq1 : 0.0f));
        o.w = hu(__floats2half2_rn(p0 ? 0.0f : wq0, p1 ? 0.0f : wq1));
        sabw4[e] = o;
    }
    if (e < UU) {
        float gl = log1pf(expf(gleak[e]));
        float c = log1pf(expf(cm[e])) * 6.0f;   // ODE_UNFOLDS=6, ts=1
        cmt[e] = c;
        gnum[e] = gl * vleak[e];
        cden[e] = c + gl + 1e-8f;
    }
}

// R7 STEP2 (best measured): scalar hexp2/hrcp (quarter-rate; R9 proved full-rate
// replacement is a wash) + packed z / packed accumulate. hrcp(inf)=0 saturates safely.
#define STEP2(A2U, B2U, WP2U, WN2U, V2U) do {                                \
    u32 z_ = hu(__hfma2(uh(A2U), uh(V2U), uh(B2U)));                         \
    __half el_ = hexp2(__ushort_as_half((unsigned short)(z_ & 0xffffu)));    \
    __half eh_ = hexp2(__ushort_as_half((unsigned short)(z_ >> 16)));        \
    __half dl_ = __hadd(el_, __float2half(1.0f));                            \
    __half dh_ = __hadd(eh_, __float2half(1.0f));                            \
    __half2 s2_ = __halves2half2(hrcp(dl_), hrcp(dh_));                      \
    accP2 = __hfma2(uh(WP2U), s2_, accP2);                                   \
    accN2 = __hfma2(uh(WN2U), s2_, accN2);                                   \
} while (0)

#define FLUSH2() do {                                                        \
    float2 fp_ = __half22float2(accP2);                                      \
    float2 fn_ = __half22float2(accN2);                                      \
    P += fp_.x + fp_.y; N += fn_.x + fn_.y;                                  \
    accP2 = uh(0u); accN2 = uh(0u);                                          \
} while (0)

// Forward pass as a TEXTUAL MACRO, not a lambda. R10's lambda capture made the
// 96 param VGPR arrays addressable -> compiler demoted them to scratch -> 13 GB of
// scratch re-reads per dispatch (FETCH_SIZE explosion, 45% VALUBusy). The macro
// expands inline at both call sites; arrays stay register-resident (rule #20).
#define FORWARD(PW) do {                                                     \
    int nbv_ = __shfl_xor(vhb, 1, 64);                                       \
    int vpk_ = (vhb & 0xffff) | (nbv_ << 16);                                \
    float P = 0.f, N = 0.f;                                                  \
    __half2 accP2 = uh(0u), accN2 = uh(0u);                                  \
    _Pragma("unroll")                                                        \
    for (int kk = 0; kk < 24; ++kk) {                                        \
        u32 v2_ = (u32)__builtin_amdgcn_readlane(vpk_, 2 * kk);              \
        STEP2(rp_a2[kk], rp_b2[kk], rp_wp2[kk], rp_wn2[kk], v2_);            \
        if ((kk & 7) == 7) FLUSH2();                                         \
    }                                                                        \
    _Pragma("unroll")                                                        \
    for (int m = 0; m < 8; ++m) {                                            \
        uint4 prr_ = rlds4[((8 * qi + m) << 8) + j];                         \
        u32 v2_ = (u32)__builtin_amdgcn_readlane(vpk_, 48 + 2 * m);          \
        STEP2(prr_.x, prr_.y, prr_.z, prr_.w, v2_);                          \
    }                                                                        \
    FLUSH2();                                                                \
    part[PW][qi][j] = make_float2(P, N);                                     \
} while (0)

// ---------------- main kernel: 1 block = 1 batch element, 16 waves ----------------
// wave (qi=wv&3, qj=wv>>2): column j = 64*qj + l.
// Recurrent row-pairs per wave: 24 in registers (pairs 24qi..+23, 96 VGPRs) + 8 from
// LDS (pairs 96+8qi..+7). v lane-distributed: lane l holds v[u(l)]; pair-packed v
// broadcast built once per forward pass with one shfl_xor; one readlane per STEP2.
//
// R11 = R10's ROTATED unfold loop {v-update -> conv-check -> STEP2s -> barrier}
// (removes the guaranteed-identity STEP2 block after convergence detection; forward
// passes per t drop from k+2 to k+1) with the forward pass macro-inlined (no lambda).
// Same dv criterion, triple-buffered flag, all breaks block-uniform.
__global__ __launch_bounds__(1024, 4) void ltc_kernel(
    const float* __restrict__ x,
    const float* __restrict__ input_w, const float* __restrict__ input_b,
    const float* __restrict__ halt_w, const float* __restrict__ halt_b,
    const float* __restrict__ out_w, const float* __restrict__ out_b,
    const uint4* __restrict__ rabw4, const uint4* __restrict__ sabw4,
    const float* __restrict__ cmt_g, const float* __restrict__ gnum_g,
    const float* __restrict__ cden_g,
    float* __restrict__ readout, float* __restrict__ h_state, float* __restrict__ ponder_out)
{
    const int b = blockIdx.x, tid = threadIdx.x;
    const int wv = tid >> 6, l = tid & 63;
    const int qi = wv & 3, qj = wv >> 2;
    const int j = (qj << 6) + l;
    const int u = (l < 48) ? (48 * qi + l) : (192 + 16 * qi + (l - 48));

    __shared__ uint4 rlds4[32 * UU];         // 128 KB: row-pairs 96..127 (rows 192..255)
    __shared__ float2 part[2][4][UU];        // 16 KB: (P,N) partials, double-buffered
    __shared__ __half2 xinh2[SS / 2];
    __shared__ float red[4];
    __shared__ int viol[3];                  // triple-buffered "dv_s violated eps" flag

    // stage LDS-resident row-pairs (once): 32*256 uint4
    for (int m = 0; m < 8; ++m) {
        int f = m * 1024 + tid;
        rlds4[f] = rabw4[96 * 256 + f];
    }

    // register-resident row-pairs (once): 96 VGPRs (pairs 24qi..24qi+23)
    u32 rp_a2[24], rp_b2[24], rp_wp2[24], rp_wn2[24];
#pragma unroll
    for (int kk = 0; kk < 24; ++kk) {
        uint4 tp = rabw4[((24 * qi + kk) << 8) + j];
        rp_a2[kk] = tp.x; rp_b2[kk] = tp.y; rp_wp2[kk] = tp.z; rp_wn2[kk] = tp.w;
    }

    const float cmtu = cmt_g[u], gnu = gnum_g[u], cdu = cden_g[u];
    const float hwu = halt_w[u], owu = out_w[u], obu = out_b[u];
    const float hb = halt_b[0];
    float iw = 0.f, ibv = 0.f;
    if (tid < SS) { iw = input_w[tid]; ibv = input_b[tid]; }

    float v = 0.0f;
    int vhb = 0;                  // f16 bits of v (for readlane broadcast)
    float pond = 0.0f;
    __syncthreads();

    for (int t = 0; t < TT; ++t) {
        // ---- input mapping (f16 for broadcast use) ----
        if (tid < SS)
            ((__half*)xinh2)[tid] =
                __float2half(fmaf(x[((size_t)b * TT + t) * SS + tid], iw, ibv));
        __syncthreads();
        if (tid == 0) viol[0] = 0;   // slot for dv_0; slots 1,2 reset by dv_0/dv_1 iters

        // ---- sensory partials: row-pairs [16qi, 16qi+16), streamed from L2 ----
        {
            float P = 0.f, N = 0.f;
            __half2 accP2 = uh(0u), accN2 = uh(0u);
#pragma unroll 1
            for (int c = 0; c < 8; ++c) {
                int p0 = 16 * qi + 2 * c;
                uint4 q0 = sabw4[(p0 << 8) + j];
                uint4 q1 = sabw4[((p0 + 1) << 8) + j];
                u32 x0 = hu(xinh2[p0]);
                u32 x1 = hu(xinh2[p0 + 1]);
                STEP2(q0.x, q0.y, q0.z, q0.w, x0);
                STEP2(q1.x, q1.y, q1.z, q1.w, x1);
                if ((c & 3) == 3) FLUSH2();
            }
            part[0][qi][j] = make_float2(P, N);
        }
        __syncthreads();
        float basen, based;
        {
            float2 s0 = part[0][0][u], s1 = part[0][1][u];
            float2 s2 = part[0][2][u], s3 = part[0][3][u];
            float Ps = s0.x + s1.x + s2.x + s3.x;
            float Ns = s0.y + s1.y + s2.y + s3.y;
            basen = (Ps - Ns) + gnu;
            based = (Ps + Ns) + cdu;
        }

        int pw = 1;                   // first forward targets slot 1 (slot 0 = sensory;
                                      // basen reads complete before slot-0 reuse, which
                                      // only happens after the next barrier)
        float accA = 0.0f, halt_sum = 0.0f, rem = 0.0f;
        int nupd = 0;
        int s = 0;                    // dv counter within this timestep
        bool tconv = false;           // fixed point reached -> remaining unfolds identity
        float pr = 0.0f;              // cached halting prob (valid while tconv)

        // ---- ACT loop (uniform early exit) ----
#pragma unroll 1
        for (int n = 0; n < 10; ++n) {
            // step-top check: catches convergence at the final v-update of the previous
            // step (flag written before the halting-phase barrier -> race-free read).
            if (!tconv && s >= 1 && viol[(s - 1) % 3] == 0) tconv = true;
            if (!tconv) {
                FORWARD(pw); __syncthreads();
#pragma unroll 1
                for (int uu = 1; uu <= 6; ++uu) {
                    // v-update from part[pw] (written by preceding forward; barriered)
                    float2 p0 = part[pw][0][u], p1 = part[pw][1][u];
                    float2 p2 = part[pw][2][u], p3 = part[pw][3][u];
                    float Pt = p0.x + p1.x + p2.x + p3.x;
                    float Nt = p0.y + p1.y + p2.y + p3.y;
                    float num = (Pt - Nt) + basen;
                    float den = (Pt + Nt) + based;
                    float vn = fmaf(cmtu, v, num) * __builtin_amdgcn_rcpf(den);
                    float dv = fabsf(vn - v);
                    v = vn;
                    vhb = (int)__half_as_ushort(__float2half(v));
                    // flag discipline: write dv_s -> slot s%3; reset slot (s+1)%3 for
                    // dv_{s+1}; read dv_{s-1}'s verdict (written last iter, barriered).
                    int aw = __all(dv <= CONV_EPS);
                    if (l == 0 && !aw) viol[s % 3] = 1;
                    if (tid == 0) viol[(s + 1) % 3] = 0;
                    bool fin = (s >= 1) && (viol[(s - 1) % 3] == 0);
                    ++s;
                    if (fin) { tconv = true; break; }   // v already final: skip STEP2s
                    if (uu == 6) break;                  // 6 unfolds complete
                    pw ^= 1;
                    FORWARD(pw); __syncthreads();
                }

                // halting p = sigmoid(v . halt_w + hb); qj==0 waves hold all 256 units
                if (qj == 0) {
                    float hp = v * hwu;
                    hp += __shfl_down(hp, 32, 64);
                    hp += __shfl_down(hp, 16, 64);
                    hp += __shfl_down(hp, 8, 64);
                    hp += __shfl_down(hp, 4, 64);
                    hp += __shfl_down(hp, 2, 64);
                    hp += __shfl_down(hp, 1, 64);
                    if (l == 0) red[qi] = hp;
                }
                __syncthreads();
                float dot = red[0] + red[1] + red[2] + red[3] + hb;
                pr = __builtin_amdgcn_rcpf(1.0f + __builtin_amdgcn_exp2f(-dot * LOG2E));
            }
            // scalar ACT accounting (exact reference semantics)
            float new_sum = halt_sum + pr;
            bool halting = (n == 9) || (new_sum >= 0.99f);
            float r = 1.0f - halt_sum;
            float wgt = halting ? r : pr;
            accA = fmaf(wgt, v, accA);
            if (halting) rem += r;
            halt_sum = new_sum;
            ++nupd;
            if (halting) break;
        }

        // ---- t epilogue: new_state = accA ----
        if (qj == 0)
            readout[((size_t)b * TT + t) * UU + u] = fmaf(accA, owu, obu);
        v = accA;
        vhb = (int)__half_as_ushort(__float2half(v));
        pond += (float)nupd + rem;
    }

    if (qj == 0) h_state[(size_t)b * UU + u] = v;
    if (tid == 0) atomicAdd(ponder_out, pond * (1.0f / BB));
}

// ---------------- launch ----------------
extern "C" void kernel_launch(void* const* d_in, const int* in_sizes, int n_in,
                              void* d_out, int out_size, void* d_ws, size_t ws_size,
                              hipStream_t stream)
{
    const float* x             = (const float*)d_in[0];
    const float* input_w       = (const float*)d_in[1];
    const float* input_b       = (const float*)d_in[2];
    const float* sensory_w     = (const float*)d_in[3];
    const float* sensory_mu    = (const float*)d_in[4];
    const float* sensory_sigma = (const float*)d_in[5];
    const float* sensory_erev  = (const float*)d_in[6];
    const float* w             = (const float*)d_in[7];
    const float* mu            = (const float*)d_in[8];
    const float* sigma         = (const float*)d_in[9];
    const float* erev          = (const float*)d_in[10];
    const float* gleak         = (const float*)d_in[11];
    const float* vleak         = (const float*)d_in[12];
    const float* cm            = (const float*)d_in[13];
    const float* output_w      = (const float*)d_in[14];
    const float* output_b      = (const float*)d_in[15];
    const float* halt_w        = (const float*)d_in[16];
    const float* halt_b        = (const float*)d_in[17];

    float* readout = (float*)d_out;
    float* h_state = readout + (size_t)BB * TT * UU;
    float* ponder  = h_state + (size_t)BB * UU;

    char* wsb = (char*)d_ws;
    uint4* rabw4 = (uint4*)wsb;  wsb += (size_t)(UU / 2) * UU * sizeof(uint4);
    uint4* sabw4 = (uint4*)wsb;  wsb += (size_t)(SS / 2) * UU * sizeof(uint4);
    float* cmt  = (float*)wsb;  wsb += (size_t)UU * 4;
    float* gnum = (float*)wsb;  wsb += (size_t)UU * 4;
    float* cden = (float*)wsb;  wsb += (size_t)UU * 4;

    (void)hipMemsetAsync(ponder, 0, sizeof(float), stream);
    prep_kernel<<<128, 256, 0, stream>>>(
        sensory_w, sensory_mu, sensory_sigma, sensory_erev,
        w, mu, sigma, erev, gleak, vleak, cm,
        rabw4, sabw4, cmt, gnum, cden);
    ltc_kernel<<<BB, 1024, 0, stream>>>(
        x, input_w, input_b, halt_w, halt_b, output_w, output_b,
        rabw4, sabw4, cmt, gnum, cden,
        readout, h_state, ponder);
}

// Round 12
// 3318.756 us; speedup vs baseline: 1.8301x; 1.1621x over previous
//
#include <hip/hip_runtime.h>
#include <hip/hip_fp16.h>

#define LOG2E 1.44269504088896340736f
#define BB 256
#define TT 128
#define SS 128
#define UU 256
// |dv| threshold for "unfold was identity" (R1/R2/R7 notes): must sit above 1 f16
// ulp of v (4.88e-4 dither); post-freeze drift <= eps*c/(1-c), c ~ 0.03-0.07 -> ~9e-5.
#define CONV_EPS 1.2e-3f

typedef unsigned int u32;

__device__ __forceinline__ __half2 uh(u32 x) { union { u32 u; __half2 h; } c; c.u = x; return c.h; }
__device__ __forceinline__ u32 hu(__half2 h) { union { u32 u; __half2 h2; } c; c.h2 = h; return c.u; }

// ---------------- parameter precompute (pair-packed) ----------------
// sigmoid(sigma*(v-mu)) = 1/(1+2^(a*v+b)), a=-sigma*log2e, b=sigma*mu*log2e
// Two consecutive pre-rows (2*i2, 2*i2+1) packed per entry:
//   uint4{ half2(a0,a1), half2(b0,b1), half2(wP0,wP1), half2(wN0,wN1) }  (16 B)
__global__ __launch_bounds__(256) void prep_kernel(
    const float* __restrict__ sensory_w, const float* __restrict__ sensory_mu,
    const float* __restrict__ sensory_sigma, const float* __restrict__ sensory_erev,
    const float* __restrict__ w, const float* __restrict__ mu,
    const float* __restrict__ sigma, const float* __restrict__ erev,
    const float* __restrict__ gleak, const float* __restrict__ vleak,
    const float* __restrict__ cm,
    uint4* __restrict__ rabw4, uint4* __restrict__ sabw4,
    float* __restrict__ cmt, float* __restrict__ gnum, float* __restrict__ cden)
{
    int e = blockIdx.x * 256 + threadIdx.x;   // e = i2*256 + j
    if (e < (UU / 2) * UU) {
        int i2 = e >> 8, j = e & 255;
        int r0 = (2 * i2) * UU + j, r1 = r0 + UU;
        float sg0 = sigma[r0], sg1 = sigma[r1];
        float m0 = mu[r0], m1 = mu[r1];
        float wq0 = log1pf(expf(w[r0])), wq1 = log1pf(expf(w[r1]));
        bool p0 = erev[r0] > 0.0f, p1 = erev[r1] > 0.0f;
        uint4 o;
        o.x = hu(__floats2half2_rn(-sg0 * LOG2E, -sg1 * LOG2E));
        o.y = hu(__floats2half2_rn(sg0 * m0 * LOG2E, sg1 * m1 * LOG2E));
        o.z = hu(__floats2half2_rn(p0 ? wq0 : 0.0f, p1 ? wq1 : 0.0f));
        o.w = hu(__floats2half2_rn(p0 ? 0.0f : wq0, p1 ? 0.0f : wq1));
        rabw4[e] = o;
    }
    if (e < (SS / 2) * UU) {
        int i2 = e >> 8, j = e & 255;
        int r0 = (2 * i2) * UU + j, r1 = r0 + UU;
        float sg0 = sensory_sigma[r0], sg1 = sensory_sigma[r1];
        float m0 = sensory_mu[r0], m1 = sensory_mu[r1];
        float wq0 = log1pf(expf(sensory_w[r0])), wq1 = log1pf(expf(sensory_w[r1]));
        bool p0 = sensory_erev[r0] > 0.0f, p1 = sensory_erev[r1] > 0.0f;
        uint4 o;
        o.x = hu(__floats2half2_rn(-sg0 * LOG2E, -sg1 * LOG2E));
        o.y = hu(__floats2half2_rn(sg0 * m0 * LOG2E, sg1 * m1 * LOG2E));
        o.z = hu(__floats2half2_rn(p0 ? wq0 : 0.0f, p1 ? wq1 : 0.0f));
        o.w = hu(__floats2half2_rn(p0 ? 0.0f : wq0, p1 ? 0.0f : wq1));
        sabw4[e] = o;
    }
    if (e < UU) {
        float gl = log1pf(expf(gleak[e]));
        float c = log1pf(expf(cm[e])) * 6.0f;   // ODE_UNFOLDS=6, ts=1
        cmt[e] = c;
        gnum[e] = gl * vleak[e];
        cden[e] = c + gl + 1e-8f;
    }
}

// R7 STEP2 (best measured): scalar hexp2/hrcp (quarter-rate; R9 proved full-rate
// replacement is a wash) + packed z / packed accumulate. hrcp(inf)=0 saturates safely.
// Generic-acc form so the sensory kernel can use per-batch-row accumulators.
#define STEP2G(A2U, B2U, WP2U, WN2U, V2U, AP, AN) do {                       \
    u32 z_ = hu(__hfma2(uh(A2U), uh(V2U), uh(B2U)));                         \
    __half el_ = hexp2(__ushort_as_half((unsigned short)(z_ & 0xffffu)));    \
    __half eh_ = hexp2(__ushort_as_half((unsigned short)(z_ >> 16)));        \
    __half dl_ = __hadd(el_, __float2half(1.0f));                            \
    __half dh_ = __hadd(eh_, __float2half(1.0f));                            \
    __half2 s2_ = __halves2half2(hrcp(dl_), hrcp(dh_));                      \
    AP = __hfma2(uh(WP2U), s2_, AP);                                         \
    AN = __hfma2(uh(WN2U), s2_, AN);                                         \
} while (0)
#define STEP2(A2U, B2U, WP2U, WN2U, V2U) STEP2G(A2U, B2U, WP2U, WN2U, V2U, accP2, accN2)

#define FLUSH2() do {                                                        \
    float2 fp_ = __half22float2(accP2);                                      \
    float2 fn_ = __half22float2(accN2);                                      \
    P += fp_.x + fp_.y; N += fn_.x + fn_.y;                                  \
    accP2 = uh(0u); accN2 = uh(0u);                                          \
} while (0)

// ---------------- sensory precompute: bnd[b][t][u] = (basen, based) ----------------
// Batch-parallel with param reuse: block = (t, 32-batch slice). Each p-row's packed
// params are loaded ONCE and applied to 8 batch rows (param L2 traffic 8.6 GB -> 1.1
// GB vs per-(b,t) evaluation). xin staged in 8 KB LDS. Accs are static-unrolled
// arrays (rule #20: all indices compile-time). gnu/cdu folded in here so the main
// kernel reads basen/based directly.
__global__ __launch_bounds__(256) void sens_kernel(
    const float* __restrict__ x,
    const float* __restrict__ input_w, const float* __restrict__ input_b,
    const uint4* __restrict__ sabw4,
    const float* __restrict__ gnum, const float* __restrict__ cden,
    float2* __restrict__ bnd)
{
    const int t = blockIdx.x >> 3;
    const int b0 = (blockIdx.x & 7) * 32;
    const int u = threadIdx.x;
    __shared__ __half sxin[32][SS];

    // stage xin for 32 batch rows (16 elements per thread, row-contiguous)
    for (int i = 0; i < 16; ++i) {
        int idx = i * 256 + threadIdx.x;      // 0..4095 = bb*128 + s
        int bb = idx >> 7, s = idx & 127;
        float xv = x[((size_t)(b0 + bb) * TT + t) * SS + s];
        sxin[bb][s] = __float2half(fmaf(xv, input_w[s], input_b[s]));
    }
    __syncthreads();

    const float gnu = gnum[u], cdu = cden[u];

#pragma unroll 1
    for (int ch = 0; ch < 4; ++ch) {          // 4 chunks x 8 batch rows
        float Pf[8], Nf[8];
        __half2 aP[8], aN[8];
#pragma unroll
        for (int bb = 0; bb < 8; ++bb) {
            Pf[bb] = 0.f; Nf[bb] = 0.f; aP[bb] = uh(0u); aN[bb] = uh(0u);
        }
#pragma unroll 1
        for (int p = 0; p < 64; ++p) {        // s row-pairs
            uint4 q = sabw4[(p << 8) + u];    // coalesced; reused for 8 batch rows
#pragma unroll
            for (int bb = 0; bb < 8; ++bb) {
                u32 x2 = hu(*(const __half2*)&sxin[ch * 8 + bb][2 * p]);  // broadcast
                STEP2G(q.x, q.y, q.z, q.w, x2, aP[bb], aN[bb]);
            }
            if ((p & 3) == 3) {               // flush every 4 pairs per acc
#pragma unroll
                for (int bb = 0; bb < 8; ++bb) {
                    float2 fp = __half22float2(aP[bb]);
                    float2 fn = __half22float2(aN[bb]);
                    Pf[bb] += fp.x + fp.y; Nf[bb] += fn.x + fn.y;
                    aP[bb] = uh(0u); aN[bb] = uh(0u);
                }
            }
        }
#pragma unroll
        for (int bb = 0; bb < 8; ++bb) {
            int bg = b0 + ch * 8 + bb;
            bnd[((size_t)bg * TT + t) * UU + u] =
                make_float2((Pf[bb] - Nf[bb]) + gnu, (Pf[bb] + Nf[bb]) + cdu);
        }
    }
}

// ---------------- main kernel: 1 block = 1 batch element, 16 waves ----------------
// R7 structure (best measured: 3699 us) minus the sensory phase (offloaded to
// sens_kernel): no xin staging, no sensory STEP2s, one fewer barrier per t.
// basen/based read as one float2 per t (latency hidden under the first unfold).
// Cross-t race check for the removed t-top barrier: halting is block-uniform, so
// every wave passed the final halting barrier of t-1 before any wave enters t; all
// prior-t viol/part reads precede that barrier, all new-t writes follow it.
__global__ __launch_bounds__(1024, 4) void ltc_kernel(
    const float* __restrict__ halt_w, const float* __restrict__ halt_b,
    const float* __restrict__ out_w, const float* __restrict__ out_b,
    const uint4* __restrict__ rabw4, const float2* __restrict__ bndg,
    const float* __restrict__ cmt_g,
    float* __restrict__ readout, float* __restrict__ h_state, float* __restrict__ ponder_out)
{
    const int b = blockIdx.x, tid = threadIdx.x;
    const int wv = tid >> 6, l = tid & 63;
    const int qi = wv & 3, qj = wv >> 2;
    const int j = (qj << 6) + l;
    const int u = (l < 48) ? (48 * qi + l) : (192 + 16 * qi + (l - 48));

    __shared__ uint4 rlds4[32 * UU];         // 128 KB: row-pairs 96..127 (rows 192..255)
    __shared__ float2 part[2][4][UU];        // 16 KB: (P,N) partials, double-buffered
    __shared__ float red[4];
    __shared__ int viol[3];                  // triple-buffered "dv violated eps" flag

    // stage LDS-resident row-pairs (once): 32*256 uint4
    for (int m = 0; m < 8; ++m) {
        int f = m * 1024 + tid;
        rlds4[f] = rabw4[96 * 256 + f];
    }

    // register-resident row-pairs (once): 96 VGPRs (pairs 24qi..24qi+23)
    u32 rp_a2[24], rp_b2[24], rp_wp2[24], rp_wn2[24];
#pragma unroll
    for (int kk = 0; kk < 24; ++kk) {
        uint4 tp = rabw4[((24 * qi + kk) << 8) + j];
        rp_a2[kk] = tp.x; rp_b2[kk] = tp.y; rp_wp2[kk] = tp.z; rp_wn2[kk] = tp.w;
    }

    const float cmtu = cmt_g[u];
    const float hwu = halt_w[u], owu = out_w[u], obu = out_b[u];
    const float hb = halt_b[0];

    float v = 0.0f;
    int vhb = 0;                  // f16 bits of v (for readlane broadcast)
    float pond = 0.0f;
    __syncthreads();

    for (int t = 0; t < TT; ++t) {
        // ---- per-t sensory terms (precomputed) ----
        float2 bv = bndg[((size_t)b * TT + t) * UU + u];
        float basen = bv.x, based = bv.y;
        if (tid == 0) viol[0] = 0;

        int pb = 1;
        float accA = 0.0f, halt_sum = 0.0f, rem = 0.0f;
        int nupd = 0;
        int g3 = 0, g = 0;
        bool tconv = false;
        float pr = 0.0f;

        // ---- ACT loop (uniform early exit) ----
#pragma unroll 1
        for (int n = 0; n < 10; ++n) {
            bool ran = !tconv;
            if (ran) {
#pragma unroll 1
                for (int uu = 0; uu < 6 && !tconv; ++uu) {
                    // pair-packed v broadcast: even lane l holds (v[u(l)], v[u(l+1)])
                    int nbv = __shfl_xor(vhb, 1, 64);
                    int vpk = (vhb & 0xffff) | (nbv << 16);

                    float P = 0.f, N = 0.f;
                    __half2 accP2 = uh(0u), accN2 = uh(0u);
#pragma unroll
                    for (int kk = 0; kk < 24; ++kk) {
                        u32 v2 = (u32)__builtin_amdgcn_readlane(vpk, 2 * kk);
                        STEP2(rp_a2[kk], rp_b2[kk], rp_wp2[kk], rp_wn2[kk], v2);
                        if ((kk & 7) == 7) FLUSH2();
                    }
#pragma unroll
                    for (int m = 0; m < 8; ++m) {
                        uint4 prr = rlds4[((8 * qi + m) << 8) + j];
                        u32 v2 = (u32)__builtin_amdgcn_readlane(vpk, 48 + 2 * m);
                        STEP2(prr.x, prr.y, prr.z, prr.w, v2);
                    }
                    FLUSH2();
                    part[pb][qi][j] = make_float2(P, N);
                    __syncthreads();
                    // redundant per-wave v-update for own units
                    float2 p0 = part[pb][0][u], p1 = part[pb][1][u];
                    float2 p2 = part[pb][2][u], p3 = part[pb][3][u];
                    float Pt = p0.x + p1.x + p2.x + p3.x;
                    float Nt = p0.y + p1.y + p2.y + p3.y;
                    float num = (Pt - Nt) + basen;
                    float den = (Pt + Nt) + based;
                    float vn = fmaf(cmtu, v, num) * __builtin_amdgcn_rcpf(den);
                    float dv = fabsf(vn - v);
                    v = vn;
                    vhb = (int)__half_as_ushort(__float2half(v));
                    // convergence bookkeeping (triple-buffered flag, lag 1)
                    int aw = __all(dv <= CONV_EPS);
                    if (l == 0 && !aw) viol[g3] = 1;
                    int gz = g3 + 1; if (gz == 3) gz = 0;
                    if (tid == 0) viol[gz] = 0;
                    if (g >= 1) {
                        int gr = g3 - 1; if (gr < 0) gr = 2;
                        if (viol[gr] == 0) tconv = true;
                    }
                    pb ^= 1; ++g; g3 = gz;
                }

                // halting p = sigmoid(v . halt_w + hb); qj==0 waves hold all 256 units
                if (qj == 0) {
                    float hp = v * hwu;
                    hp += __shfl_down(hp, 32, 64);
                    hp += __shfl_down(hp, 16, 64);
                    hp += __shfl_down(hp, 8, 64);
                    hp += __shfl_down(hp, 4, 64);
                    hp += __shfl_down(hp, 2, 64);
                    hp += __shfl_down(hp, 1, 64);
                    if (l == 0) red[qi] = hp;
                }
                __syncthreads();
                float dot = red[0] + red[1] + red[2] + red[3] + hb;
                pr = __builtin_amdgcn_rcpf(1.0f + __builtin_amdgcn_exp2f(-dot * LOG2E));
            }
            // scalar ACT accounting (exact reference semantics)
            float new_sum = halt_sum + pr;
            bool halting = (n == 9) || (new_sum >= 0.99f);
            float r = 1.0f - halt_sum;
            float wgt = halting ? r : pr;
            accA = fmaf(wgt, v, accA);
            if (halting) rem += r;
            halt_sum = new_sum;
            ++nupd;
            if (halting) break;
        }

        // ---- t epilogue: new_state = accA ----
        if (qj == 0)
            readout[((size_t)b * TT + t) * UU + u] = fmaf(accA, owu, obu);
        v = accA;
        vhb = (int)__half_as_ushort(__float2half(v));
        pond += (float)nupd + rem;
    }

    if (qj == 0) h_state[(size_t)b * UU + u] = v;
    if (tid == 0) atomicAdd(ponder_out, pond * (1.0f / BB));
}

// ---------------- launch ----------------
extern "C" void kernel_launch(void* const* d_in, const int* in_sizes, int n_in,
                              void* d_out, int out_size, void* d_ws, size_t ws_size,
                              hipStream_t stream)
{
    const float* x             = (const float*)d_in[0];
    const float* input_w       = (const float*)d_in[1];
    const float* input_b       = (const float*)d_in[2];
    const float* sensory_w     = (const float*)d_in[3];
    const float* sensory_mu    = (const float*)d_in[4];
    const float* sensory_sigma = (const float*)d_in[5];
    const float* sensory_erev  = (const float*)d_in[6];
    const float* w             = (const float*)d_in[7];
    const float* mu            = (const float*)d_in[8];
    const float* sigma         = (const float*)d_in[9];
    const float* erev          = (const float*)d_in[10];
    const float* gleak         = (const float*)d_in[11];
    const float* vleak         = (const float*)d_in[12];
    const float* cm            = (const float*)d_in[13];
    const float* output_w      = (const float*)d_in[14];
    const float* output_b      = (const float*)d_in[15];
    const float* halt_w        = (const float*)d_in[16];
    const float* halt_b        = (const float*)d_in[17];

    float* readout = (float*)d_out;
    float* h_state = readout + (size_t)BB * TT * UU;
    float* ponder  = h_state + (size_t)BB * UU;

    char* wsb = (char*)d_ws;
    uint4* rabw4 = (uint4*)wsb;  wsb += (size_t)(UU / 2) * UU * sizeof(uint4);
    uint4* sabw4 = (uint4*)wsb;  wsb += (size_t)(SS / 2) * UU * sizeof(uint4);
    float* cmt  = (float*)wsb;  wsb += (size_t)UU * 4;
    float* gnum = (float*)wsb;  wsb += (size_t)UU * 4;
    float* cden = (float*)wsb;  wsb += (size_t)UU * 4;
    float2* bnd = (float2*)wsb; wsb += (size_t)BB * TT * UU * sizeof(float2);

    (void)hipMemsetAsync(ponder, 0, sizeof(float), stream);
    prep_kernel<<<128, 256, 0, stream>>>(
        sensory_w, sensory_mu, sensory_sigma, sensory_erev,
        w, mu, sigma, erev, gleak, vleak, cm,
        rabw4, sabw4, cmt, gnum, cden);
    sens_kernel<<<TT * 8, 256, 0, stream>>>(
        x, input_w, input_b, sabw4, gnum, cden, bnd);
    ltc_kernel<<<BB, 1024, 0, stream>>>(
        halt_w, halt_b, output_w, output_b,
        rabw4, bnd, cmt,
        readout, h_state, ponder);
}

// Round 13
// 3079.690 us; speedup vs baseline: 1.9721x; 1.0776x over previous
//
#include <hip/hip_runtime.h>
#include <hip/hip_fp16.h>

#define LOG2E 1.44269504088896340736f
#define BB 256
#define TT 128
#define SS 128
#define UU 256
// |dv| threshold for "unfold was identity" (R1/R2/R7 notes): must sit above 1 f16
// ulp of v (4.88e-4 dither); post-freeze drift <= eps*c/(1-c), c ~ 0.03-0.07 -> ~9e-5.
#define CONV_EPS 1.2e-3f

typedef unsigned int u32;
typedef _Float16 f16x2 __attribute__((ext_vector_type(2)));

__device__ __forceinline__ __half2 uh(u32 x) { union { u32 u; __half2 h; } c; c.u = x; return c.h; }
__device__ __forceinline__ u32 hu(__half2 h) { union { u32 u; __half2 h2; } c; c.h2 = h; return c.u; }

// f16-pair dot with f32 accumulate: one full-rate v_dot2_f32_f16 replaces
// {hfma2 into f16 acc + periodic f32 flush} -> -15% instr and better accuracy.
__device__ __forceinline__ float fdot2u(u32 a, u32 b, float c) {
#if __has_builtin(__builtin_amdgcn_fdot2)
    union { u32 u; f16x2 v; } A, B; A.u = a; B.u = b;
    return __builtin_amdgcn_fdot2(A.v, B.v, c, false);
#else
    float2 p = __half22float2(__hmul2(uh(a), uh(b)));
    return c + p.x + p.y;
#endif
}

// ---------------- parameter precompute (pair-packed) ----------------
// sigmoid(sigma*(v-mu)) = 1/(1+2^(a*v+b)), a=-sigma*log2e, b=sigma*mu*log2e
// Two consecutive pre-rows (2*i2, 2*i2+1) packed per entry:
//   uint4{ half2(a0,a1), half2(b0,b1), half2(wP0,wP1), half2(wN0,wN1) }  (16 B)
__global__ __launch_bounds__(256) void prep_kernel(
    const float* __restrict__ sensory_w, const float* __restrict__ sensory_mu,
    const float* __restrict__ sensory_sigma, const float* __restrict__ sensory_erev,
    const float* __restrict__ w, const float* __restrict__ mu,
    const float* __restrict__ sigma, const float* __restrict__ erev,
    const float* __restrict__ gleak, const float* __restrict__ vleak,
    const float* __restrict__ cm,
    uint4* __restrict__ rabw4, uint4* __restrict__ sabw4,
    float* __restrict__ cmt, float* __restrict__ gnum, float* __restrict__ cden)
{
    int e = blockIdx.x * 256 + threadIdx.x;   // e = i2*256 + j
    if (e < (UU / 2) * UU) {
        int i2 = e >> 8, j = e & 255;
        int r0 = (2 * i2) * UU + j, r1 = r0 + UU;
        float sg0 = sigma[r0], sg1 = sigma[r1];
        float m0 = mu[r0], m1 = mu[r1];
        float wq0 = log1pf(expf(w[r0])), wq1 = log1pf(expf(w[r1]));
        bool p0 = erev[r0] > 0.0f, p1 = erev[r1] > 0.0f;
        uint4 o;
        o.x = hu(__floats2half2_rn(-sg0 * LOG2E, -sg1 * LOG2E));
        o.y = hu(__floats2half2_rn(sg0 * m0 * LOG2E, sg1 * m1 * LOG2E));
        o.z = hu(__floats2half2_rn(p0 ? wq0 : 0.0f, p1 ? wq1 : 0.0f));
        o.w = hu(__floats2half2_rn(p0 ? 0.0f : wq0, p1 ? 0.0f : wq1));
        rabw4[e] = o;
    }
    if (e < (SS / 2) * UU) {
        int i2 = e >> 8, j = e & 255;
        int r0 = (2 * i2) * UU + j, r1 = r0 + UU;
        float sg0 = sensory_sigma[r0], sg1 = sensory_sigma[r1];
        float m0 = sensory_mu[r0], m1 = sensory_mu[r1];
        float wq0 = log1pf(expf(sensory_w[r0])), wq1 = log1pf(expf(sensory_w[r1]));
        bool p0 = sensory_erev[r0] > 0.0f, p1 = sensory_erev[r1] > 0.0f;
        uint4 o;
        o.x = hu(__floats2half2_rn(-sg0 * LOG2E, -sg1 * LOG2E));
        o.y = hu(__floats2half2_rn(sg0 * m0 * LOG2E, sg1 * m1 * LOG2E));
        o.z = hu(__floats2half2_rn(p0 ? wq0 : 0.0f, p1 ? wq1 : 0.0f));
        o.w = hu(__floats2half2_rn(p0 ? 0.0f : wq0, p1 ? 0.0f : wq1));
        sabw4[e] = o;
    }
    if (e < UU) {
        float gl = log1pf(expf(gleak[e]));
        float c = log1pf(expf(cm[e])) * 6.0f;   // ODE_UNFOLDS=6, ts=1
        cmt[e] = c;
        gnum[e] = gl * vleak[e];
        cden[e] = c + gl + 1e-8f;
    }
}

// R13 STEP2: scalar hexp2/hrcp (R9: full-rate replacement is a wash) + packed z +
// v_dot2_f32_f16 accumulate (replaces f16 acc + FLUSH2 entirely). Generic-acc form
// so both kernels share it; FP/FN are f32 accumulators.
#define STEP2G(A2U, B2U, WP2U, WN2U, V2U, FP, FN) do {                       \
    u32 z_ = hu(__hfma2(uh(A2U), uh(V2U), uh(B2U)));                         \
    __half el_ = hexp2(__ushort_as_half((unsigned short)(z_ & 0xffffu)));    \
    __half eh_ = hexp2(__ushort_as_half((unsigned short)(z_ >> 16)));        \
    __half dl_ = __hadd(el_, __float2half(1.0f));                            \
    __half dh_ = __hadd(eh_, __float2half(1.0f));                            \
    u32 s2u_ = hu(__halves2half2(hrcp(dl_), hrcp(dh_)));                     \
    FP = fdot2u((WP2U), s2u_, FP);                                           \
    FN = fdot2u((WN2U), s2u_, FN);                                           \
} while (0)
#define STEP2(A2U, B2U, WP2U, WN2U, V2U) STEP2G(A2U, B2U, WP2U, WN2U, V2U, P, N)

// ---------------- sensory precompute: bnd[b][t][u] = (basen, based) ----------------
// Batch-parallel with param reuse: block = (t, 32-batch slice). Each p-row's packed
// params are loaded ONCE and applied to 8 batch rows. xin staged in 8 KB LDS.
// Accs are static-unrolled f32 arrays (rule #20). gnu/cdu folded in here.
__global__ __launch_bounds__(256) void sens_kernel(
    const float* __restrict__ x,
    const float* __restrict__ input_w, const float* __restrict__ input_b,
    const uint4* __restrict__ sabw4,
    const float* __restrict__ gnum, const float* __restrict__ cden,
    float2* __restrict__ bnd)
{
    const int t = blockIdx.x >> 3;
    const int b0 = (blockIdx.x & 7) * 32;
    const int u = threadIdx.x;
    __shared__ __half sxin[32][SS];

    // stage xin for 32 batch rows (16 elements per thread, row-contiguous)
    for (int i = 0; i < 16; ++i) {
        int idx = i * 256 + threadIdx.x;      // 0..4095 = bb*128 + s
        int bb = idx >> 7, s = idx & 127;
        float xv = x[((size_t)(b0 + bb) * TT + t) * SS + s];
        sxin[bb][s] = __float2half(fmaf(xv, input_w[s], input_b[s]));
    }
    __syncthreads();

    const float gnu = gnum[u], cdu = cden[u];

#pragma unroll 1
    for (int ch = 0; ch < 4; ++ch) {          // 4 chunks x 8 batch rows
        float Pf[8], Nf[8];
#pragma unroll
        for (int bb = 0; bb < 8; ++bb) { Pf[bb] = 0.f; Nf[bb] = 0.f; }
#pragma unroll 1
        for (int p = 0; p < 64; ++p) {        // s row-pairs
            uint4 q = sabw4[(p << 8) + u];    // coalesced; reused for 8 batch rows
#pragma unroll
            for (int bb = 0; bb < 8; ++bb) {
                u32 x2 = hu(*(const __half2*)&sxin[ch * 8 + bb][2 * p]);  // broadcast
                STEP2G(q.x, q.y, q.z, q.w, x2, Pf[bb], Nf[bb]);
            }
        }
#pragma unroll
        for (int bb = 0; bb < 8; ++bb) {
            int bg = b0 + ch * 8 + bb;
            bnd[((size_t)bg * TT + t) * UU + u] =
                make_float2((Pf[bb] - Nf[bb]) + gnu, (Pf[bb] + Nf[bb]) + cdu);
        }
    }
}

// ---------------- main kernel: 1 block = 1 batch element, 16 waves ----------------
// R12 structure (best measured: ltc 3206 us @ 81.8% VALUBusy) with fdot2 accumulate.
// wave (qi=wv&3, qj=wv>>2): column j = 64*qj + l. 24 reg pairs + 8 LDS pairs per
// wave; v lane-distributed; pair-packed v broadcast via one shfl_xor; one readlane
// per STEP2. 1 barrier per unfold; convergence skip via triple-buffered viol flag.
__global__ __launch_bounds__(1024, 4) void ltc_kernel(
    const float* __restrict__ halt_w, const float* __restrict__ halt_b,
    const float* __restrict__ out_w, const float* __restrict__ out_b,
    const uint4* __restrict__ rabw4, const float2* __restrict__ bndg,
    const float* __restrict__ cmt_g,
    float* __restrict__ readout, float* __restrict__ h_state, float* __restrict__ ponder_out)
{
    const int b = blockIdx.x, tid = threadIdx.x;
    const int wv = tid >> 6, l = tid & 63;
    const int qi = wv & 3, qj = wv >> 2;
    const int j = (qj << 6) + l;
    const int u = (l < 48) ? (48 * qi + l) : (192 + 16 * qi + (l - 48));

    __shared__ uint4 rlds4[32 * UU];         // 128 KB: row-pairs 96..127 (rows 192..255)
    __shared__ float2 part[2][4][UU];        // 16 KB: (P,N) partials, double-buffered
    __shared__ float red[4];
    __shared__ int viol[3];                  // triple-buffered "dv violated eps" flag

    // stage LDS-resident row-pairs (once): 32*256 uint4
    for (int m = 0; m < 8; ++m) {
        int f = m * 1024 + tid;
        rlds4[f] = rabw4[96 * 256 + f];
    }

    // register-resident row-pairs (once): 96 VGPRs (pairs 24qi..24qi+23)
    u32 rp_a2[24], rp_b2[24], rp_wp2[24], rp_wn2[24];
#pragma unroll
    for (int kk = 0; kk < 24; ++kk) {
        uint4 tp = rabw4[((24 * qi + kk) << 8) + j];
        rp_a2[kk] = tp.x; rp_b2[kk] = tp.y; rp_wp2[kk] = tp.z; rp_wn2[kk] = tp.w;
    }

    const float cmtu = cmt_g[u];
    const float hwu = halt_w[u], owu = out_w[u], obu = out_b[u];
    const float hb = halt_b[0];

    float v = 0.0f;
    int vhb = 0;                  // f16 bits of v (for readlane broadcast)
    float pond = 0.0f;
    __syncthreads();

    for (int t = 0; t < TT; ++t) {
        // ---- per-t sensory terms (precomputed by sens_kernel) ----
        float2 bv = bndg[((size_t)b * TT + t) * UU + u];
        float basen = bv.x, based = bv.y;
        if (tid == 0) viol[0] = 0;

        int pb = 1;
        float accA = 0.0f, halt_sum = 0.0f, rem = 0.0f;
        int nupd = 0;
        int g3 = 0, g = 0;
        bool tconv = false;
        float pr = 0.0f;

        // ---- ACT loop (uniform early exit) ----
#pragma unroll 1
        for (int n = 0; n < 10; ++n) {
            bool ran = !tconv;
            if (ran) {
#pragma unroll 1
                for (int uu = 0; uu < 6 && !tconv; ++uu) {
                    // pair-packed v broadcast: even lane l holds (v[u(l)], v[u(l+1)])
                    int nbv = __shfl_xor(vhb, 1, 64);
                    int vpk = (vhb & 0xffff) | (nbv << 16);

                    float P = 0.f, N = 0.f;
#pragma unroll
                    for (int kk = 0; kk < 24; ++kk) {
                        u32 v2 = (u32)__builtin_amdgcn_readlane(vpk, 2 * kk);
                        STEP2(rp_a2[kk], rp_b2[kk], rp_wp2[kk], rp_wn2[kk], v2);
                    }
#pragma unroll
                    for (int m = 0; m < 8; ++m) {
                        uint4 prr = rlds4[((8 * qi + m) << 8) + j];
                        u32 v2 = (u32)__builtin_amdgcn_readlane(vpk, 48 + 2 * m);
                        STEP2(prr.x, prr.y, prr.z, prr.w, v2);
                    }
                    part[pb][qi][j] = make_float2(P, N);
                    __syncthreads();
                    // redundant per-wave v-update for own units
                    float2 p0 = part[pb][0][u], p1 = part[pb][1][u];
                    float2 p2 = part[pb][2][u], p3 = part[pb][3][u];
                    float Pt = p0.x + p1.x + p2.x + p3.x;
                    float Nt = p0.y + p1.y + p2.y + p3.y;
                    float num = (Pt - Nt) + basen;
                    float den = (Pt + Nt) + based;
                    float vn = fmaf(cmtu, v, num) * __builtin_amdgcn_rcpf(den);
                    float dv = fabsf(vn - v);
                    v = vn;
                    vhb = (int)__half_as_ushort(__float2half(v));
                    // convergence bookkeeping (triple-buffered flag, lag 1)
                    int aw = __all(dv <= CONV_EPS);
                    if (l == 0 && !aw) viol[g3] = 1;
                    int gz = g3 + 1; if (gz == 3) gz = 0;
                    if (tid == 0) viol[gz] = 0;
                    if (g >= 1) {
                        int gr = g3 - 1; if (gr < 0) gr = 2;
                        if (viol[gr] == 0) tconv = true;
                    }
                    pb ^= 1; ++g; g3 = gz;
                }

                // halting p = sigmoid(v . halt_w + hb); qj==0 waves hold all 256 units
                if (qj == 0) {
                    float hp = v * hwu;
                    hp += __shfl_down(hp, 32, 64);
                    hp += __shfl_down(hp, 16, 64);
                    hp += __shfl_down(hp, 8, 64);
                    hp += __shfl_down(hp, 4, 64);
                    hp += __shfl_down(hp, 2, 64);
                    hp += __shfl_down(hp, 1, 64);
                    if (l == 0) red[qi] = hp;
                }
                __syncthreads();
                float dot = red[0] + red[1] + red[2] + red[3] + hb;
                pr = __builtin_amdgcn_rcpf(1.0f + __builtin_amdgcn_exp2f(-dot * LOG2E));
            }
            // scalar ACT accounting (exact reference semantics)
            float new_sum = halt_sum + pr;
            bool halting = (n == 9) || (new_sum >= 0.99f);
            float r = 1.0f - halt_sum;
            float wgt = halting ? r : pr;
            accA = fmaf(wgt, v, accA);
            if (halting) rem += r;
            halt_sum = new_sum;
            ++nupd;
            if (halting) break;
        }

        // ---- t epilogue: new_state = accA ----
        if (qj == 0)
            readout[((size_t)b * TT + t) * UU + u] = fmaf(accA, owu, obu);
        v = accA;
        vhb = (int)__half_as_ushort(__float2half(v));
        pond += (float)nupd + rem;
    }

    if (qj == 0) h_state[(size_t)b * UU + u] = v;
    if (tid == 0) atomicAdd(ponder_out, pond * (1.0f / BB));
}

// ---------------- launch ----------------
extern "C" void kernel_launch(void* const* d_in, const int* in_sizes, int n_in,
                              void* d_out, int out_size, void* d_ws, size_t ws_size,
                              hipStream_t stream)
{
    const float* x             = (const float*)d_in[0];
    const float* input_w       = (const float*)d_in[1];
    const float* input_b       = (const float*)d_in[2];
    const float* sensory_w     = (const float*)d_in[3];
    const float* sensory_mu    = (const float*)d_in[4];
    const float* sensory_sigma = (const float*)d_in[5];
    const float* sensory_erev  = (const float*)d_in[6];
    const float* w             = (const float*)d_in[7];
    const float* mu            = (const float*)d_in[8];
    const float* sigma         = (const float*)d_in[9];
    const float* erev          = (const float*)d_in[10];
    const float* gleak         = (const float*)d_in[11];
    const float* vleak         = (const float*)d_in[12];
    const float* cm            = (const float*)d_in[13];
    const float* output_w      = (const float*)d_in[14];
    const float* output_b      = (const float*)d_in[15];
    const float* halt_w        = (const float*)d_in[16];
    const float* halt_b        = (const float*)d_in[17];

    float* readout = (float*)d_out;
    float* h_state = readout + (size_t)BB * TT * UU;
    float* ponder  = h_state + (size_t)BB * UU;

    char* wsb = (char*)d_ws;
    uint4* rabw4 = (uint4*)wsb;  wsb += (size_t)(UU / 2) * UU * sizeof(uint4);
    uint4* sabw4 = (uint4*)wsb;  wsb += (size_t)(SS / 2) * UU * sizeof(uint4);
    float* cmt  = (float*)wsb;  wsb += (size_t)UU * 4;
    float* gnum = (float*)wsb;  wsb += (size_t)UU * 4;
    float* cden = (float*)wsb;  wsb += (size_t)UU * 4;
    float2* bnd = (float2*)wsb; wsb += (size_t)BB * TT * UU * sizeof(float2);

    (void)hipMemsetAsync(ponder, 0, sizeof(float), stream);
    prep_kernel<<<128, 256, 0, stream>>>(
        sensory_w, sensory_mu, sensory_sigma, sensory_erev,
        w, mu, sigma, erev, gleak, vleak, cm,
        rabw4, sabw4, cmt, gnum, cden);
    sens_kernel<<<TT * 8, 256, 0, stream>>>(
        x, input_w, input_b, sabw4, gnum, cden, bnd);
    ltc_kernel<<<BB, 1024, 0, stream>>>(
        halt_w, halt_b, output_w, output_b,
        rabw4, bnd, cmt,
        readout, h_state, ponder);
}

// Round 14
// 2912.263 us; speedup vs baseline: 2.0855x; 1.0575x over previous
//
#include <hip/hip_runtime.h>
#include <hip/hip_fp16.h>

#define LOG2E 1.44269504088896340736f
#define BB 256
#define TT 128
#define SS 128
#define UU 256
// |dv| threshold for "unfold was identity". R14: raised 1.2e-3 -> 2.4e-3. v is
// broadcast as f16, so converged units dither at 1 ulp of |v|: 9.8e-4 for |v| in
// [1,2) but 2.0e-3 for |v| in [2,4). 1.2e-3 sat INSIDE the ladder: a tile with any
// unit |v|>=2 dithered above eps and never detected convergence (full 6 x nACT
// unfolds -- the R1 failure mode one rung up). 2.4e-3 clears the band to |v|<4.
// Post-freeze drift <= eps*c/(1-c) ~ 1.6e-4 (c ~ 0.06), << f16 output noise 2e-3.
#define CONV_EPS 2.4e-3f

typedef unsigned int u32;
typedef _Float16 f16x2 __attribute__((ext_vector_type(2)));

__device__ __forceinline__ __half2 uh(u32 x) { union { u32 u; __half2 h; } c; c.u = x; return c.h; }
__device__ __forceinline__ u32 hu(__half2 h) { union { u32 u; __half2 h2; } c; c.h2 = h; return c.u; }

// f16-pair dot with f32 accumulate: one full-rate v_dot2_f32_f16 replaces
// {hfma2 into f16 acc + periodic f32 flush} (R13: -15% instr, better accuracy).
__device__ __forceinline__ float fdot2u(u32 a, u32 b, float c) {
#if __has_builtin(__builtin_amdgcn_fdot2)
    union { u32 u; f16x2 v; } A, B; A.u = a; B.u = b;
    return __builtin_amdgcn_fdot2(A.v, B.v, c, false);
#else
    float2 p = __half22float2(__hmul2(uh(a), uh(b)));
    return c + p.x + p.y;
#endif
}

// ---------------- parameter precompute (pair-packed) ----------------
// sigmoid(sigma*(v-mu)) = 1/(1+2^(a*v+b)), a=-sigma*log2e, b=sigma*mu*log2e
// Two consecutive pre-rows (2*i2, 2*i2+1) packed per entry:
//   uint4{ half2(a0,a1), half2(b0,b1), half2(wP0,wP1), half2(wN0,wN1) }  (16 B)
__global__ __launch_bounds__(256) void prep_kernel(
    const float* __restrict__ sensory_w, const float* __restrict__ sensory_mu,
    const float* __restrict__ sensory_sigma, const float* __restrict__ sensory_erev,
    const float* __restrict__ w, const float* __restrict__ mu,
    const float* __restrict__ sigma, const float* __restrict__ erev,
    const float* __restrict__ gleak, const float* __restrict__ vleak,
    const float* __restrict__ cm,
    uint4* __restrict__ rabw4, uint4* __restrict__ sabw4,
    float* __restrict__ cmt, float* __restrict__ gnum, float* __restrict__ cden)
{
    int e = blockIdx.x * 256 + threadIdx.x;   // e = i2*256 + j
    if (e < (UU / 2) * UU) {
        int i2 = e >> 8, j = e & 255;
        int r0 = (2 * i2) * UU + j, r1 = r0 + UU;
        float sg0 = sigma[r0], sg1 = sigma[r1];
        float m0 = mu[r0], m1 = mu[r1];
        float wq0 = log1pf(expf(w[r0])), wq1 = log1pf(expf(w[r1]));
        bool p0 = erev[r0] > 0.0f, p1 = erev[r1] > 0.0f;
        uint4 o;
        o.x = hu(__floats2half2_rn(-sg0 * LOG2E, -sg1 * LOG2E));
        o.y = hu(__floats2half2_rn(sg0 * m0 * LOG2E, sg1 * m1 * LOG2E));
        o.z = hu(__floats2half2_rn(p0 ? wq0 : 0.0f, p1 ? wq1 : 0.0f));
        o.w = hu(__floats2half2_rn(p0 ? 0.0f : wq0, p1 ? 0.0f : wq1));
        rabw4[e] = o;
    }
    if (e < (SS / 2) * UU) {
        int i2 = e >> 8, j = e & 255;
        int r0 = (2 * i2) * UU + j, r1 = r0 + UU;
        float sg0 = sensory_sigma[r0], sg1 = sensory_sigma[r1];
        float m0 = sensory_mu[r0], m1 = sensory_mu[r1];
        float wq0 = log1pf(expf(sensory_w[r0])), wq1 = log1pf(expf(sensory_w[r1]));
        bool p0 = sensory_erev[r0] > 0.0f, p1 = sensory_erev[r1] > 0.0f;
        uint4 o;
        o.x = hu(__floats2half2_rn(-sg0 * LOG2E, -sg1 * LOG2E));
        o.y = hu(__floats2half2_rn(sg0 * m0 * LOG2E, sg1 * m1 * LOG2E));
        o.z = hu(__floats2half2_rn(p0 ? wq0 : 0.0f, p1 ? wq1 : 0.0f));
        o.w = hu(__floats2half2_rn(p0 ? 0.0f : wq0, p1 ? 0.0f : wq1));
        sabw4[e] = o;
    }
    if (e < UU) {
        float gl = log1pf(expf(gleak[e]));
        float c = log1pf(expf(cm[e])) * 6.0f;   // ODE_UNFOLDS=6, ts=1
        cmt[e] = c;
        gnum[e] = gl * vleak[e];
        cden[e] = c + gl + 1e-8f;
    }
}

// R13 STEP2: scalar hexp2/hrcp (R9: full-rate replacement is a wash) + packed z +
// v_dot2_f32_f16 accumulate. Generic-acc form; FP/FN are f32 accumulators.
#define STEP2G(A2U, B2U, WP2U, WN2U, V2U, FP, FN) do {                       \
    u32 z_ = hu(__hfma2(uh(A2U), uh(V2U), uh(B2U)));                         \
    __half el_ = hexp2(__ushort_as_half((unsigned short)(z_ & 0xffffu)));    \
    __half eh_ = hexp2(__ushort_as_half((unsigned short)(z_ >> 16)));        \
    __half dl_ = __hadd(el_, __float2half(1.0f));                            \
    __half dh_ = __hadd(eh_, __float2half(1.0f));                            \
    u32 s2u_ = hu(__halves2half2(hrcp(dl_), hrcp(dh_)));                     \
    FP = fdot2u((WP2U), s2u_, FP);                                           \
    FN = fdot2u((WN2U), s2u_, FN);                                           \
} while (0)
#define STEP2(A2U, B2U, WP2U, WN2U, V2U) STEP2G(A2U, B2U, WP2U, WN2U, V2U, P, N)

// ---------------- sensory precompute: bnd[b][t][u] = (basen, based) ----------------
// Batch-parallel with param reuse: block = (t, 32-batch slice). Each p-row's packed
// params are loaded ONCE and applied to 8 batch rows. xin staged in 8 KB LDS.
// Accs are static-unrolled f32 arrays (rule #20). gnu/cdu folded in here.
__global__ __launch_bounds__(256) void sens_kernel(
    const float* __restrict__ x,
    const float* __restrict__ input_w, const float* __restrict__ input_b,
    const uint4* __restrict__ sabw4,
    const float* __restrict__ gnum, const float* __restrict__ cden,
    float2* __restrict__ bnd)
{
    const int t = blockIdx.x >> 3;
    const int b0 = (blockIdx.x & 7) * 32;
    const int u = threadIdx.x;
    __shared__ __half sxin[32][SS];

    // stage xin for 32 batch rows (16 elements per thread, row-contiguous)
    for (int i = 0; i < 16; ++i) {
        int idx = i * 256 + threadIdx.x;      // 0..4095 = bb*128 + s
        int bb = idx >> 7, s = idx & 127;
        float xv = x[((size_t)(b0 + bb) * TT + t) * SS + s];
        sxin[bb][s] = __float2half(fmaf(xv, input_w[s], input_b[s]));
    }
    __syncthreads();

    const float gnu = gnum[u], cdu = cden[u];

#pragma unroll 1
    for (int ch = 0; ch < 4; ++ch) {          // 4 chunks x 8 batch rows
        float Pf[8], Nf[8];
#pragma unroll
        for (int bb = 0; bb < 8; ++bb) { Pf[bb] = 0.f; Nf[bb] = 0.f; }
#pragma unroll 1
        for (int p = 0; p < 64; ++p) {        // s row-pairs
            uint4 q = sabw4[(p << 8) + u];    // coalesced; reused for 8 batch rows
#pragma unroll
            for (int bb = 0; bb < 8; ++bb) {
                u32 x2 = hu(*(const __half2*)&sxin[ch * 8 + bb][2 * p]);  // broadcast
                STEP2G(q.x, q.y, q.z, q.w, x2, Pf[bb], Nf[bb]);
            }
        }
#pragma unroll
        for (int bb = 0; bb < 8; ++bb) {
            int bg = b0 + ch * 8 + bb;
            bnd[((size_t)bg * TT + t) * UU + u] =
                make_float2((Pf[bb] - Nf[bb]) + gnu, (Pf[bb] + Nf[bb]) + cdu);
        }
    }
}

// ---------------- main kernel: 1 block = 1 batch element, 16 waves ----------------
// R13 structure (best measured: ltc 2972 us @ 84.1% VALUBusy), CONV_EPS fix only.
// wave (qi=wv&3, qj=wv>>2): column j = 64*qj + l. 24 reg pairs + 8 LDS pairs per
// wave; v lane-distributed; pair-packed v broadcast via one shfl_xor; one readlane
// per STEP2. 1 barrier per unfold; convergence skip via triple-buffered viol flag.
__global__ __launch_bounds__(1024, 4) void ltc_kernel(
    const float* __restrict__ halt_w, const float* __restrict__ halt_b,
    const float* __restrict__ out_w, const float* __restrict__ out_b,
    const uint4* __restrict__ rabw4, const float2* __restrict__ bndg,
    const float* __restrict__ cmt_g,
    float* __restrict__ readout, float* __restrict__ h_state, float* __restrict__ ponder_out)
{
    const int b = blockIdx.x, tid = threadIdx.x;
    const int wv = tid >> 6, l = tid & 63;
    const int qi = wv & 3, qj = wv >> 2;
    const int j = (qj << 6) + l;
    const int u = (l < 48) ? (48 * qi + l) : (192 + 16 * qi + (l - 48));

    __shared__ uint4 rlds4[32 * UU];         // 128 KB: row-pairs 96..127 (rows 192..255)
    __shared__ float2 part[2][4][UU];        // 16 KB: (P,N) partials, double-buffered
    __shared__ float red[4];
    __shared__ int viol[3];                  // triple-buffered "dv violated eps" flag

    // stage LDS-resident row-pairs (once): 32*256 uint4
    for (int m = 0; m < 8; ++m) {
        int f = m * 1024 + tid;
        rlds4[f] = rabw4[96 * 256 + f];
    }

    // register-resident row-pairs (once): 96 VGPRs (pairs 24qi..24qi+23)
    u32 rp_a2[24], rp_b2[24], rp_wp2[24], rp_wn2[24];
#pragma unroll
    for (int kk = 0; kk < 24; ++kk) {
        uint4 tp = rabw4[((24 * qi + kk) << 8) + j];
        rp_a2[kk] = tp.x; rp_b2[kk] = tp.y; rp_wp2[kk] = tp.z; rp_wn2[kk] = tp.w;
    }

    const float cmtu = cmt_g[u];
    const float hwu = halt_w[u], owu = out_w[u], obu = out_b[u];
    const float hb = halt_b[0];

    float v = 0.0f;
    int vhb = 0;                  // f16 bits of v (for readlane broadcast)
    float pond = 0.0f;
    __syncthreads();

    for (int t = 0; t < TT; ++t) {
        // ---- per-t sensory terms (precomputed by sens_kernel) ----
        float2 bv = bndg[((size_t)b * TT + t) * UU + u];
        float basen = bv.x, based = bv.y;
        if (tid == 0) viol[0] = 0;

        int pb = 1;
        float accA = 0.0f, halt_sum = 0.0f, rem = 0.0f;
        int nupd = 0;
        int g3 = 0, g = 0;
        bool tconv = false;
        float pr = 0.0f;

        // ---- ACT loop (uniform early exit) ----
#pragma unroll 1
        for (int n = 0; n < 10; ++n) {
            bool ran = !tconv;
            if (ran) {
#pragma unroll 1
                for (int uu = 0; uu < 6 && !tconv; ++uu) {
                    // pair-packed v broadcast: even lane l holds (v[u(l)], v[u(l+1)])
                    int nbv = __shfl_xor(vhb, 1, 64);
                    int vpk = (vhb & 0xffff) | (nbv << 16);

                    float P = 0.f, N = 0.f;
#pragma unroll
                    for (int kk = 0; kk < 24; ++kk) {
                        u32 v2 = (u32)__builtin_amdgcn_readlane(vpk, 2 * kk);
                        STEP2(rp_a2[kk], rp_b2[kk], rp_wp2[kk], rp_wn2[kk], v2);
                    }
#pragma unroll
                    for (int m = 0; m < 8; ++m) {
                        uint4 prr = rlds4[((8 * qi + m) << 8) + j];
                        u32 v2 = (u32)__builtin_amdgcn_readlane(vpk, 48 + 2 * m);
                        STEP2(prr.x, prr.y, prr.z, prr.w, v2);
                    }
                    part[pb][qi][j] = make_float2(P, N);
                    __syncthreads();
                    // redundant per-wave v-update for own units
                    float2 p0 = part[pb][0][u], p1 = part[pb][1][u];
                    float2 p2 = part[pb][2][u], p3 = part[pb][3][u];
                    float Pt = p0.x + p1.x + p2.x + p3.x;
                    float Nt = p0.y + p1.y + p2.y + p3.y;
                    float num = (Pt - Nt) + basen;
                    float den = (Pt + Nt) + based;
                    float vn = fmaf(cmtu, v, num) * __builtin_amdgcn_rcpf(den);
                    float dv = fabsf(vn - v);
                    v = vn;
                    vhb = (int)__half_as_ushort(__float2half(v));
                    // convergence bookkeeping (triple-buffered flag, lag 1)
                    int aw = __all(dv <= CONV_EPS);
                    if (l == 0 && !aw) viol[g3] = 1;
                    int gz = g3 + 1; if (gz == 3) gz = 0;
                    if (tid == 0) viol[gz] = 0;
                    if (g >= 1) {
                        int gr = g3 - 1; if (gr < 0) gr = 2;
                        if (viol[gr] == 0) tconv = true;
                    }
                    pb ^= 1; ++g; g3 = gz;
                }

                // halting p = sigmoid(v . halt_w + hb); qj==0 waves hold all 256 units
                if (qj == 0) {
                    float hp = v * hwu;
                    hp += __shfl_down(hp, 32, 64);
                    hp += __shfl_down(hp, 16, 64);
                    hp += __shfl_down(hp, 8, 64);
                    hp += __shfl_down(hp, 4, 64);
                    hp += __shfl_down(hp, 2, 64);
                    hp += __shfl_down(hp, 1, 64);
                    if (l == 0) red[qi] = hp;
                }
                __syncthreads();
                float dot = red[0] + red[1] + red[2] + red[3] + hb;
                pr = __builtin_amdgcn_rcpf(1.0f + __builtin_amdgcn_exp2f(-dot * LOG2E));
            }
            // scalar ACT accounting (exact reference semantics)
            float new_sum = halt_sum + pr;
            bool halting = (n == 9) || (new_sum >= 0.99f);
            float r = 1.0f - halt_sum;
            float wgt = halting ? r : pr;
            accA = fmaf(wgt, v, accA);
            if (halting) rem += r;
            halt_sum = new_sum;
            ++nupd;
            if (halting) break;
        }

        // ---- t epilogue: new_state = accA ----
        if (qj == 0)
            readout[((size_t)b * TT + t) * UU + u] = fmaf(accA, owu, obu);
        v = accA;
        vhb = (int)__half_as_ushort(__float2half(v));
        pond += (float)nupd + rem;
    }

    if (qj == 0) h_state[(size_t)b * UU + u] = v;
    if (tid == 0) atomicAdd(ponder_out, pond * (1.0f / BB));
}

// ---------------- launch ----------------
extern "C" void kernel_launch(void* const* d_in, const int* in_sizes, int n_in,
                              void* d_out, int out_size, void* d_ws, size_t ws_size,
                              hipStream_t stream)
{
    const float* x             = (const float*)d_in[0];
    const float* input_w       = (const float*)d_in[1];
    const float* input_b       = (const float*)d_in[2];
    const float* sensory_w     = (const float*)d_in[3];
    const float* sensory_mu    = (const float*)d_in[4];
    const float* sensory_sigma = (const float*)d_in[5];
    const float* sensory_erev  = (const float*)d_in[6];
    const float* w             = (const float*)d_in[7];
    const float* mu            = (const float*)d_in[8];
    const float* sigma         = (const float*)d_in[9];
    const float* erev          = (const float*)d_in[10];
    const float* gleak         = (const float*)d_in[11];
    const float* vleak         = (const float*)d_in[12];
    const float* cm            = (const float*)d_in[13];
    const float* output_w      = (const float*)d_in[14];
    const float* output_b      = (const float*)d_in[15];
    const float* halt_w        = (const float*)d_in[16];
    const float* halt_b        = (const float*)d_in[17];

    float* readout = (float*)d_out;
    float* h_state = readout + (size_t)BB * TT * UU;
    float* ponder  = h_state + (size_t)BB * UU;

    char* wsb = (char*)d_ws;
    uint4* rabw4 = (uint4*)wsb;  wsb += (size_t)(UU / 2) * UU * sizeof(uint4);
    uint4* sabw4 = (uint4*)wsb;  wsb += (size_t)(SS / 2) * UU * sizeof(uint4);
    float* cmt  = (float*)wsb;  wsb += (size_t)UU * 4;
    float* gnum = (float*)wsb;  wsb += (size_t)UU * 4;
    float* cden = (float*)wsb;  wsb += (size_t)UU * 4;
    float2* bnd = (float2*)wsb; wsb += (size_t)BB * TT * UU * sizeof(float2);

    (void)hipMemsetAsync(ponder, 0, sizeof(float), stream);
    prep_kernel<<<128, 256, 0, stream>>>(
        sensory_w, sensory_mu, sensory_sigma, sensory_erev,
        w, mu, sigma, erev, gleak, vleak, cm,
        rabw4, sabw4, cmt, gnum, cden);
    sens_kernel<<<TT * 8, 256, 0, stream>>>(
        x, input_w, input_b, sabw4, gnum, cden, bnd);
    ltc_kernel<<<BB, 1024, 0, stream>>>(
        halt_w, halt_b, output_w, output_b,
        rabw4, bnd, cmt,
        readout, h_state, ponder);
}